// Round 1
// baseline (2067.975 us; speedup 1.0000x reference)
//
#include <hip/hip_runtime.h>

// Problem constants (from reference setup_inputs)
//   N = 100,000 atoms, E = 6,400,000 directed edges
// Inputs:  d_in[0] pos   [N,3] f32
//          d_in[1] sigma scalar f32
//          d_in[2] eps   scalar f32
//          d_in[3] edge_index [2,E] i32  (src = first E, dst = second E)
// Output:  d_out[0] = energy (f32), d_out[1 .. 3N] = atom_force [N,3] f32

__global__ __launch_bounds__(256) void pairforce_kernel(
    const float* __restrict__ pos,
    const float* __restrict__ sigma_p,
    const float* __restrict__ eps_p,
    const int*   __restrict__ src,
    const int*   __restrict__ dst,
    float* __restrict__ energy_out,   // d_out[0]
    float* __restrict__ force_out,    // d_out + 1, [N,3]
    int nEdges)
{
    const int i = blockIdx.x * blockDim.x + threadIdx.x;

    const float sigma = sigma_p[0];
    const float eps   = eps_p[0];
    const float sig2  = sigma * sigma;

    float v = 0.0f;

    if (i < nEdges) {
        const int s = src[i];
        const int d = dst[i];

        const float dx = pos[3 * s + 0] - pos[3 * d + 0];
        const float dy = pos[3 * s + 1] - pos[3 * d + 1];
        const float dz = pos[3 * s + 2] - pos[3 * d + 2];

        const float r2     = dx * dx + dy * dy + dz * dz;
        const float inv_r2 = 1.0f / r2;
        const float s2     = sig2 * inv_r2;
        const float sr6    = s2 * s2 * s2;
        const float sr12   = sr6 * sr6;

        // energy term
        v = 4.0f * eps * (sr12 - sr6);

        // atom_force = -grad/2 = 12*eps*(2*sr12 - sr6)/r^2 * d  (toward src)
        const float fs = 12.0f * eps * (2.0f * sr12 - sr6) * inv_r2;
        const float fx = fs * dx;
        const float fy = fs * dy;
        const float fz = fs * dz;

        atomicAdd(&force_out[3 * s + 0],  fx);
        atomicAdd(&force_out[3 * s + 1],  fy);
        atomicAdd(&force_out[3 * s + 2],  fz);
        atomicAdd(&force_out[3 * d + 0], -fx);
        atomicAdd(&force_out[3 * d + 1], -fy);
        atomicAdd(&force_out[3 * d + 2], -fz);
    }

    // ---- block-level energy reduction: wave shuffle (64-wide) then LDS ----
    #pragma unroll
    for (int off = 32; off > 0; off >>= 1)
        v += __shfl_down(v, off, 64);

    __shared__ float part[4];            // 256 threads = 4 waves
    const int lane = threadIdx.x & 63;
    const int wid  = threadIdx.x >> 6;
    if (lane == 0) part[wid] = v;
    __syncthreads();

    if (threadIdx.x == 0) {
        const float t = part[0] + part[1] + part[2] + part[3];
        atomicAdd(energy_out, t);
    }
}

extern "C" void kernel_launch(void* const* d_in, const int* in_sizes, int n_in,
                              void* d_out, int out_size, void* d_ws, size_t ws_size,
                              hipStream_t stream)
{
    const float* pos     = (const float*)d_in[0];
    const float* sigma_p = (const float*)d_in[1];
    const float* eps_p   = (const float*)d_in[2];
    const int*   edge    = (const int*)d_in[3];

    const int nEdges = in_sizes[3] / 2;      // edge_index is [2, E]
    const int* src = edge;
    const int* dst = edge + nEdges;

    float* out = (float*)d_out;

    // d_out is poisoned with 0xAA before every call — zero it (capture-safe).
    hipMemsetAsync(d_out, 0, (size_t)out_size * sizeof(float), stream);

    const int block = 256;
    const int grid  = (nEdges + block - 1) / block;
    pairforce_kernel<<<grid, block, 0, stream>>>(
        pos, sigma_p, eps_p, src, dst,
        out,        // energy at d_out[0]
        out + 1,    // forces at d_out[1..]
        nEdges);
}

// Round 2
// 2043.627 us; speedup vs baseline: 1.0119x; 1.0119x over previous
//
#include <hip/hip_runtime.h>

// N = 100,000 atoms, E = 6,400,000 directed edges.
// d_in[0] pos [N,3] f32 | d_in[1] sigma | d_in[2] eps | d_in[3] edge_index [2,E] i32
// d_out[0] = energy, d_out[1..3N] = atom_force [N,3] f32
//
// Strategy: 8 force-buffer replicas (one per XCD) in d_ws. Atomics use
// WORKGROUP memory scope so the RMW is performed in the issuing XCD's L2
// (no device-scope write-through to HBM). Replica index = physical XCD id
// read from HW_REG_XCC_ID, so all atomics to replica k funnel through XCD
// k's L2 -> atomicity holds without cross-XCD coherence. Kernel-boundary
// release flushes dirty L2; a reduce kernel folds 8 replicas into d_out.

#define NREP 8

__device__ __forceinline__ int xcd_id() {
    int x;
    asm volatile("s_getreg_b32 %0, hwreg(HW_REG_XCC_ID, 0, 32)" : "=s"(x));
    return x & (NREP - 1);
}

__device__ __forceinline__ void fadd_local(float* p, float v) {
    // workgroup scope: no sc1 bypass -> RMW stays in this XCD's L2
    __hip_atomic_fetch_add(p, v, __ATOMIC_RELAXED, __HIP_MEMORY_SCOPE_WORKGROUP);
}

__global__ __launch_bounds__(256) void pairforce_edges(
    const float* __restrict__ pos,
    const float* __restrict__ sigma_p,
    const float* __restrict__ eps_p,
    const int*   __restrict__ src,
    const int*   __restrict__ dst,
    float* __restrict__ frep,        // [NREP, 3N] force replicas
    float* __restrict__ erep,        // [NREP]     energy partials
    int nEdges, int strideRep)
{
    const int i = blockIdx.x * blockDim.x + threadIdx.x;
    const int rep = xcd_id();
    float* f = frep + (size_t)rep * strideRep;

    const float sigma = sigma_p[0];
    const float eps   = eps_p[0];
    const float sig2  = sigma * sigma;

    float v = 0.0f;

    if (i < nEdges) {
        const int s = src[i];
        const int d = dst[i];

        const float dx = pos[3 * s + 0] - pos[3 * d + 0];
        const float dy = pos[3 * s + 1] - pos[3 * d + 1];
        const float dz = pos[3 * s + 2] - pos[3 * d + 2];

        const float r2     = dx * dx + dy * dy + dz * dz;
        const float inv_r2 = 1.0f / r2;
        const float s2     = sig2 * inv_r2;
        const float sr6    = s2 * s2 * s2;
        const float sr12   = sr6 * sr6;

        v = 4.0f * eps * (sr12 - sr6);

        const float fs = 12.0f * eps * (2.0f * sr12 - sr6) * inv_r2;
        const float fx = fs * dx;
        const float fy = fs * dy;
        const float fz = fs * dz;

        fadd_local(&f[3 * s + 0],  fx);
        fadd_local(&f[3 * s + 1],  fy);
        fadd_local(&f[3 * s + 2],  fz);
        fadd_local(&f[3 * d + 0], -fx);
        fadd_local(&f[3 * d + 1], -fy);
        fadd_local(&f[3 * d + 2], -fz);
    }

    // block energy reduction: 64-wide shuffle, then LDS, one atomic per block
    #pragma unroll
    for (int off = 32; off > 0; off >>= 1)
        v += __shfl_down(v, off, 64);

    __shared__ float part[4];
    const int lane = threadIdx.x & 63;
    const int wid  = threadIdx.x >> 6;
    if (lane == 0) part[wid] = v;
    __syncthreads();

    if (threadIdx.x == 0)
        fadd_local(&erep[rep], part[0] + part[1] + part[2] + part[3]);
}

__global__ __launch_bounds__(256) void pairforce_reduce(
    const float* __restrict__ frep,
    const float* __restrict__ erep,
    float* __restrict__ out,         // d_out: [0]=energy, [1..3N]=forces
    int n3, int strideRep)
{
    const int i = blockIdx.x * blockDim.x + threadIdx.x;
    if (i < n3) {
        float acc = 0.0f;
        #pragma unroll
        for (int r = 0; r < NREP; ++r)
            acc += frep[(size_t)r * strideRep + i];
        out[1 + i] = acc;
    }
    if (i == 0) {
        float e = 0.0f;
        #pragma unroll
        for (int r = 0; r < NREP; ++r)
            e += erep[r];
        out[0] = e;
    }
}

extern "C" void kernel_launch(void* const* d_in, const int* in_sizes, int n_in,
                              void* d_out, int out_size, void* d_ws, size_t ws_size,
                              hipStream_t stream)
{
    const float* pos     = (const float*)d_in[0];
    const float* sigma_p = (const float*)d_in[1];
    const float* eps_p   = (const float*)d_in[2];
    const int*   edge    = (const int*)d_in[3];

    const int nEdges = in_sizes[3] / 2;        // edge_index is [2, E]
    const int* src = edge;
    const int* dst = edge + nEdges;

    const int n3        = out_size - 1;        // 3*N
    const int strideRep = n3;

    float* frep = (float*)d_ws;                    // NREP * n3 floats
    float* erep = frep + (size_t)NREP * strideRep; // NREP floats

    // zero replicas + energy partials (ws is poisoned 0xAA before each call)
    hipMemsetAsync(d_ws, 0, ((size_t)NREP * strideRep + NREP) * sizeof(float),
                   stream);

    const int block = 256;
    const int grid1 = (nEdges + block - 1) / block;
    pairforce_edges<<<grid1, block, 0, stream>>>(
        pos, sigma_p, eps_p, src, dst, frep, erep, nEdges, strideRep);

    const int grid2 = (n3 + block - 1) / block;
    pairforce_reduce<<<grid2, block, 0, stream>>>(frep, erep, (float*)d_out,
                                                  n3, strideRep);
}

// Round 3
// 314.918 us; speedup vs baseline: 6.5667x; 6.4894x over previous
//
#include <hip/hip_runtime.h>

// N = 100,000 atoms, E = 6,400,000 directed edges.
// d_in[0] pos [N,3] f32 | d_in[1] sigma | d_in[2] eps | d_in[3] edge_index [2,E] i32
// d_out[0] = energy, d_out[1..3N] = atom_force [N,3] f32
//
// R2 evidence: global scatter atomics execute at the fabric/MALL point
// (32 B/transaction, ~20 G/s) regardless of memory scope -> 1955 us.
// R3 strategy: ZERO global atomics. Atoms partitioned into NBINS bins;
// each block owns (bin b, edge-chunk c), accumulates its bin's forces in
// LDS (ds_add_f32), then writes the whole bin slab to a private ws row
// with plain coalesced stores. A reduce kernel sums the chunk rows.

#define NBINS      8
#define BIN_ATOMS  12800            // 8 * 12800 = 102,400 >= 100,000
#define BIN_F      (BIN_ATOMS * 3)  // 38,400 floats = 150 KiB
#define ROW_F      (NBINS * BIN_F)  // 307,200 floats per chunk-row
#define BLOCK      1024
#define MAXCHUNKS  32

__global__ __launch_bounds__(BLOCK, 1) void pairforce_binned(
    const float* __restrict__ pos,
    const float* __restrict__ sigma_p,
    const float* __restrict__ eps_p,
    const int*   __restrict__ src,
    const int*   __restrict__ dst,
    float* __restrict__ frep,        // [nChunks][ROW_F]
    float* __restrict__ erep,        // [nChunks * NBINS]
    int nEdges, int chunkEdges)
{
    extern __shared__ float sh[];    // BIN_F force floats + 16 energy partials
    const int t = threadIdx.x;
    const int b = blockIdx.x % NBINS;   // bin
    const int c = blockIdx.x / NBINS;   // edge chunk

    // zero LDS (force slab + energy partials): (38400+16)/4 = 9604 float4s
    for (int j = t; j < (BIN_F + 16) / 4; j += BLOCK)
        ((float4*)sh)[j] = make_float4(0.f, 0.f, 0.f, 0.f);
    __syncthreads();

    const float sigma = sigma_p[0];
    const float eps   = eps_p[0];
    const float sig2  = sigma * sigma;
    const int binStart = b * BIN_ATOMS;

    const int start = c * chunkEdges;              // multiple of 4
    const int end   = min(start + chunkEdges, nEdges);

    const int4* src4 = (const int4*)src;
    const int4* dst4 = (const int4*)dst;

    float ev = 0.0f;

    for (int i4 = (start >> 2) + t; i4 < (end >> 2); i4 += BLOCK) {
        const int4 s4 = src4[i4];
        const int4 d4 = dst4[i4];
        #pragma unroll
        for (int k = 0; k < 4; ++k) {
            const int s = (k == 0) ? s4.x : (k == 1) ? s4.y : (k == 2) ? s4.z : s4.w;
            const int d = (k == 0) ? d4.x : (k == 1) ? d4.y : (k == 2) ? d4.z : d4.w;
            const unsigned ls = (unsigned)(s - binStart);
            const unsigned ld = (unsigned)(d - binStart);
            const bool hs = ls < BIN_ATOMS;
            const bool hd = ld < BIN_ATOMS;
            if (hs | hd) {
                const float dx = pos[3 * s + 0] - pos[3 * d + 0];
                const float dy = pos[3 * s + 1] - pos[3 * d + 1];
                const float dz = pos[3 * s + 2] - pos[3 * d + 2];
                const float r2     = dx * dx + dy * dy + dz * dz;
                const float inv_r2 = 1.0f / r2;
                const float s2     = sig2 * inv_r2;
                const float sr6    = s2 * s2 * s2;
                const float sr12   = sr6 * sr6;
                const float fs = 12.0f * eps * (2.0f * sr12 - sr6) * inv_r2;
                const float fx = fs * dx;
                const float fy = fs * dy;
                const float fz = fs * dz;
                if (hs) {
                    atomicAdd(&sh[3 * ls + 0],  fx);
                    atomicAdd(&sh[3 * ls + 1],  fy);
                    atomicAdd(&sh[3 * ls + 2],  fz);
                    ev += 4.0f * eps * (sr12 - sr6);   // energy counted once, in src's bin
                }
                if (hd) {
                    atomicAdd(&sh[3 * ld + 0], -fx);
                    atomicAdd(&sh[3 * ld + 1], -fy);
                    atomicAdd(&sh[3 * ld + 2], -fz);
                }
            }
        }
    }

    // per-wave energy partials into LDS tail
    #pragma unroll
    for (int off = 32; off > 0; off >>= 1)
        ev += __shfl_down(ev, off, 64);
    if ((t & 63) == 0) sh[BIN_F + (t >> 6)] = ev;
    __syncthreads();

    // flush bin slab to its private ws segment: plain coalesced float4 stores
    float4* outSeg = (float4*)(frep + (size_t)c * ROW_F + (size_t)b * BIN_F);
    for (int j = t; j < BIN_F / 4; j += BLOCK)
        outSeg[j] = ((float4*)sh)[j];

    if (t == 0) {
        float e = 0.f;
        #pragma unroll
        for (int w = 0; w < 16; ++w) e += sh[BIN_F + w];
        erep[blockIdx.x] = e;
    }
}

__global__ __launch_bounds__(256) void pairforce_reduce(
    const float* __restrict__ frep,
    const float* __restrict__ erep,
    float* __restrict__ out,          // [0]=energy, [1..n3]=forces
    int n3, int nChunks, int nPart)
{
    const int i = blockIdx.x * 256 + threadIdx.x;
    if (i < n3) {
        float acc = 0.f;
        for (int c = 0; c < nChunks; ++c)
            acc += frep[(size_t)c * ROW_F + i];
        out[1 + i] = acc;
    }
    if (blockIdx.x == gridDim.x - 1) {      // energy fold
        float e = 0.f;
        for (int j = threadIdx.x; j < nPart; j += 256) e += erep[j];
        #pragma unroll
        for (int off = 32; off > 0; off >>= 1) e += __shfl_down(e, off, 64);
        __shared__ float ep[4];
        if ((threadIdx.x & 63) == 0) ep[threadIdx.x >> 6] = e;
        __syncthreads();
        if (threadIdx.x == 0) out[0] = ep[0] + ep[1] + ep[2] + ep[3];
    }
}

extern "C" void kernel_launch(void* const* d_in, const int* in_sizes, int n_in,
                              void* d_out, int out_size, void* d_ws, size_t ws_size,
                              hipStream_t stream)
{
    const float* pos     = (const float*)d_in[0];
    const float* sigma_p = (const float*)d_in[1];
    const float* eps_p   = (const float*)d_in[2];
    const int*   edge    = (const int*)d_in[3];

    const int nEdges = in_sizes[3] / 2;      // edge_index is [2, E]
    const int* src = edge;
    const int* dst = edge + nEdges;

    const int n3 = out_size - 1;             // 3*N

    const size_t rowBytes = (size_t)ROW_F * sizeof(float);
    int nChunks = (int)((ws_size - 4096) / rowBytes);
    if (nChunks > MAXCHUNKS) nChunks = MAXCHUNKS;
    if (nChunks < 1) nChunks = 1;

    // chunk size: multiple of 4 so int4 loads are exact and aligned
    const int chunkEdges = (((nEdges + nChunks - 1) / nChunks) + 3) & ~3;

    float* frep = (float*)d_ws;
    float* erep = frep + (size_t)nChunks * ROW_F;

    const size_t shbytes = (size_t)(BIN_F + 16) * sizeof(float);  // 150 KiB + 64 B

    const int grid1 = nChunks * NBINS;
    pairforce_binned<<<grid1, BLOCK, shbytes, stream>>>(
        pos, sigma_p, eps_p, src, dst, frep, erep, nEdges, chunkEdges);

    const int grid2 = (n3 + 255) / 256;
    pairforce_reduce<<<grid2, 256, 0, stream>>>(
        frep, erep, (float*)d_out, n3, nChunks, nChunks * NBINS);
}